// Round 7
// baseline (86.120 us; speedup 1.0000x reference)
//
#include <hip/hip_runtime.h>
#include <math.h>

constexpr int BB = 2, NN = 4096, MM = 16384;
constexpr int RT = 128, CT = 128;        // block tile (rows=sampled, cols=raw)
constexpr unsigned INFBITS = 0x7F800000u;

__global__ __launch_bounds__(256) void init_ws_kernel(unsigned* ws, int n) {
    int i = blockIdx.x * 256 + threadIdx.x;
    if (i < n) ws[i] = INFBITS;
}

// grid (MM/CT, NN/RT, BB) = (128,32,2); block 256 = 16 tx (cols) x 16 ty (rows)
// 8x8 thread tile. KEY CHANGE vs R6: the q-loop is a REAL loop (unroll 2), so
// the 32 r-floats are loop-carried registers the allocator cannot re-read from
// LDS (R4-R6 failure: full unroll let the scheduler sink rT reads per-q ->
// LDS-pipe bound, VGPR=48). Row-min is reduced in-loop (tree + 4 shfl + atomic)
// to avoid a runtime-indexed array (scratch, rule #20).
// LDS layouts: sT transposed (slot q*16+ty -> bank 4*ty, broadcast conflict-free),
// rT additive-swizzled (2-way max, free).
__global__ __launch_bounds__(256, 4) void pair_kernel(
    const float* __restrict__ sampled,   // [BB][NN][4]
    const float* __restrict__ raw,       // [BB][MM][4]
    unsigned* __restrict__ rowmin,       // [BB][NN]  float bits, atomicMin
    unsigned* __restrict__ colmin)       // [BB][MM]  float bits, atomicMin
{
    __shared__ float4 sT[RT];            // (x,y,z,|s|^2), slot = (i&7)*16 + (i>>3)
    __shared__ float4 rT[CT];            // (-2x,-2y,-2z,|r|^2), slot = (j&~7)|((j+(j>>3))&7)
    __shared__ float cred[4][CT];

    const int b  = blockIdx.z;
    const int i0 = blockIdx.y * RT;
    const int j0 = blockIdx.x * CT;
    const int tid = threadIdx.x;
    const int tx = tid & 15, ty = tid >> 4;

    const float4* sb = (const float4*)sampled + (size_t)b * NN + i0;
    const float4* rb = (const float4*)raw     + (size_t)b * MM + j0;

    if (tid < RT) {
        const int i = tid;
        float4 v = sb[i];
        v.w = fmaf(v.z, v.z, fmaf(v.y, v.y, v.x * v.x));
        sT[((i & 7) << 4) | (i >> 3)] = v;          // transposed store
    } else {
        const int j = tid - RT;
        float4 v = rb[j];
        float w = fmaf(v.z, v.z, fmaf(v.y, v.y, v.x * v.x));
        rT[(j & ~7) | ((j + (j >> 3)) & 7)] =
            make_float4(-2.f * v.x, -2.f * v.y, -2.f * v.z, w);
    }
    __syncthreads();

    // one-time: this thread's 8 raw points -> registers (loop-carried below)
    float rx[8], ry[8], rz[8], rn[8];
#pragma unroll
    for (int r = 0; r < 8; ++r) {
        float4 v = rT[(tx << 3) | ((r + tx) & 7)];  // de-swizzle, 2-way banks
        rx[r] = v.x; ry[r] = v.y; rz[r] = v.z; rn[r] = v.w;
    }

    const float INF = __uint_as_float(INFBITS);
    float cmin[8] = {INF, INF, INF, INF, INF, INF, INF, INF};

    unsigned* rowp = rowmin + (size_t)b * NN + i0 + ty * 8;

#pragma unroll 2
    for (int q = 0; q < 8; ++q) {
        float4 sv = sT[(q << 4) + ty];              // 16-lane broadcast, bank 4*ty
        float a[8];
#pragma unroll
        for (int r = 0; r < 8; ++r) {
            float t = sv.w + rn[r];
            t = fmaf(sv.x, rx[r], t);
            t = fmaf(sv.y, ry[r], t);
            t = fmaf(sv.z, rz[r], t);
            a[r] = t;
            cmin[r] = fminf(cmin[r], t);
        }
        float m0 = fminf(fminf(a[0], a[1]), fminf(a[2], a[3]));
        float m1 = fminf(fminf(a[4], a[5]), fminf(a[6], a[7]));
        float m  = fminf(m0, m1);
        m = fminf(m, __shfl_xor(m, 1, 64));
        m = fminf(m, __shfl_xor(m, 2, 64));
        m = fminf(m, __shfl_xor(m, 4, 64));
        m = fminf(m, __shfl_xor(m, 8, 64));
        if (tx == 0)
            atomicMin(&rowp[q], __float_as_uint(fmaxf(m, 0.f)));
    }

    // ---- col mins: in-wave across ty (masks 16,32), then LDS across waves ----
#pragma unroll
    for (int m = 16; m < 64; m <<= 1) {
#pragma unroll
        for (int r = 0; r < 8; ++r)
            cmin[r] = fminf(cmin[r], __shfl_xor(cmin[r], m, 64));
    }
    const int w = tid >> 6, lane = tid & 63;
    if (lane < 16) {
#pragma unroll
        for (int r = 0; r < 8; ++r) cred[w][lane * 8 + r] = cmin[r];
    }
    __syncthreads();
    if (tid < CT) {
        float v = fminf(fminf(cred[0][tid], cred[1][tid]),
                        fminf(cred[2][tid], cred[3][tid]));
        atomicMin(&colmin[(size_t)b * MM + j0 + tid],
                  __float_as_uint(fmaxf(v, 0.f)));
    }
}

// 64 blocks: b = k>>5, slice s = k&31
__global__ __launch_bounds__(256) void reduce1_kernel(
    const unsigned* __restrict__ rowmin,
    const unsigned* __restrict__ colmin,
    float* __restrict__ part)
{
    const int k = blockIdx.x, b = k >> 5, s = k & 31;
    const int tid = threadIdx.x;
    constexpr int CS = MM / 32, RS = NN / 32;

    float sB = 0.f;
    const unsigned* cm = colmin + (size_t)b * MM + s * CS;
    for (int j = tid; j < CS; j += 256) sB += sqrtf(__uint_as_float(cm[j]));

    float sF = 0.f, mF = 0.f;
    const unsigned* rm = rowmin + (size_t)b * NN + s * RS;
    for (int i = tid; i < RS; i += 256) {
        float d = sqrtf(__uint_as_float(rm[i]));
        sF += d; mF = fmaxf(mF, d);
    }
    for (int m = 1; m < 64; m <<= 1) {
        sB += __shfl_xor(sB, m, 64);
        sF += __shfl_xor(sF, m, 64);
        mF = fmaxf(mF, __shfl_xor(mF, m, 64));
    }
    __shared__ float red[3][4];
    const int lane = tid & 63, w = tid >> 6;
    if (lane == 0) { red[0][w] = sB; red[1][w] = sF; red[2][w] = mF; }
    __syncthreads();
    if (tid == 0) {
        sB = red[0][0] + red[0][1] + red[0][2] + red[0][3];
        sF = red[1][0] + red[1][1] + red[1][2] + red[1][3];
        mF = fmaxf(fmaxf(red[2][0], red[2][1]), fmaxf(red[2][2], red[2][3]));
        part[k * 3 + 0] = sB; part[k * 3 + 1] = sF; part[k * 3 + 2] = mF;
    }
}

__global__ void reduce2_kernel(const float* __restrict__ part,
                               float* __restrict__ out)
{
    const int lane = threadIdx.x;   // 64 threads; lanes 0..31 = b0, 32..63 = b1
    float sB = part[lane * 3 + 0];
    float sF = part[lane * 3 + 1];
    float mF = part[lane * 3 + 2];
    for (int m = 1; m < 32; m <<= 1) {
        sB += __shfl_xor(sB, m, 64);
        sF += __shfl_xor(sF, m, 64);
        mF = fmaxf(mF, __shfl_xor(mF, m, 64));
    }
    float oB = __shfl_xor(sB, 32, 64);
    float oF = __shfl_xor(sF, 32, 64);
    float oM = __shfl_xor(mF, 32, 64);
    if (lane == 0) {
        float l0 = 5.f * sB / (float)MM + sF / (float)NN + mF;
        float l1 = 5.f * oB / (float)MM + oF / (float)NN + oM;
        *out = 0.5f * (l0 + l1);
    }
}

extern "C" void kernel_launch(void* const* d_in, const int* in_sizes, int n_in,
                              void* d_out, int out_size, void* d_ws, size_t ws_size,
                              hipStream_t stream) {
    const float* sampled = (const float*)d_in[0];
    const float* raw     = (const float*)d_in[1];
    unsigned* rowmin = (unsigned*)d_ws;
    unsigned* colmin = rowmin + (size_t)BB * NN;
    float*    part   = (float*)(colmin + (size_t)BB * MM);
    float*    out    = (float*)d_out;

    const int ninit = BB * NN + BB * MM;
    init_ws_kernel<<<(ninit + 255) / 256, 256, 0, stream>>>((unsigned*)d_ws, ninit);
    pair_kernel<<<dim3(MM / CT, NN / RT, BB), 256, 0, stream>>>(sampled, raw, rowmin, colmin);
    reduce1_kernel<<<64, 256, 0, stream>>>(rowmin, colmin, part);
    reduce2_kernel<<<1, 64, 0, stream>>>(part, out);
}